// Round 2
// baseline (190.554 us; speedup 1.0000x reference)
//
#include <hip/hip_runtime.h>

#define HDIM 20
#define BLOCK 256

typedef __fp16 half8 __attribute__((ext_vector_type(8)));
typedef __fp16 half2v __attribute__((ext_vector_type(2)));
typedef float  float4v __attribute__((ext_vector_type(4)));
typedef int    int4v  __attribute__((ext_vector_type(4)));

static __device__ __forceinline__ float4v mfma16(half8 a, half8 b, float4v c) {
    return __builtin_amdgcn_mfma_f32_16x16x32_f16(a, b, c, 0, 0, 0);
}

// KEY INVARIANT (why there is NO cross-lane traffic in the 200-step loop):
//   B-row permutation: k = 8q + i  <->  hidden unit 4i + q   (i<5; i=5,6 pad; k=7(q=0) bias=1).
//   C/D layout (m89): lane (q,el) holds D rows 4q..4q+3 of column el.
//   A rows arranged so tile T, row 4q'+g = unit 4T+q', gate type g in {r,z,nI,nH}
//   -> lane (q,el) computes h_new for units {4T+q}, which are EXACTLY its own
//      B rows k=8q+T. The "allgather" is the identity: pack own h to fp16, done.
// A rows pre-scaled: r,z by -log2e ; nI,nH by +2log2e (tanh via 1-2/(1+exp2)).
//
// v3 (this round): DUAL-STREAM waves. rocprof showed v2 still ~35% idle with
// pipes unsaturated -> latency-bound convoy: 2 identical waves/SIMD phase-lock
// on the step-boundary MFMA wait. Now each wave runs TWO independent
// 16-element recurrences (32 els/wave, 1024 waves, 1 wave/SIMD): stream A's
// MFMA latency is statically covered by stream B's issue + trans chains.
// A-fragments shared between streams. Arithmetic bit-identical to v2.

__global__ __launch_bounds__(BLOCK, 1) void gru_decoder_kernel(
    const float* __restrict__ hidden,
    const float* __restrict__ w_ih,
    const float* __restrict__ w_hh,
    const float* __restrict__ b_ih,
    const float* __restrict__ b_hh,
    const float* __restrict__ w_l,
    const float* __restrict__ b_l,
    const int*  __restrict__ step_ptr,
    float* __restrict__ out,
    int B)
{
    const int tid = threadIdx.x;
    const int l   = tid & 63;
    const int wv  = tid >> 6;
    const int el  = l & 15;
    const int q   = l >> 4;
    const int eA  = (blockIdx.x * 4 + wv) * 32 + el;   // stream A element
    const int eB  = eA + 16;                           // stream B element
    const int step = *step_ptr;

    const float NL2E  = -1.4426950408889634f;   // r,z scale
    const float T2L2E =  2.8853900817779268f;   // n scale

    // ---- A fragments (once, shared by both streams). Lane holds k=8q..8q+7;
    // A row m=el of tile T is unit 4T+(el>>2), gate type el&3 {0:r,1:z,2:nI,3:nH}. ----
    const int u_dst = el >> 2;
    const int g     = el & 3;

    half8 Afold[5], Azero[5], Ay;
    #pragma unroll
    for (int T = 0; T < 5; ++T) {
        const int u  = 4 * T + u_dst;
        const int rr = (g == 0) ? u : (g == 1) ? 20 + u : 40 + u;
        const float sc = (g <= 1) ? NL2E : T2L2E;
        half8 hf, h0;
        #pragma unroll
        for (int j = 0; j < 8; ++j) {
            float af = 0.f, a0 = 0.f;
            if (j < 5) {
                const int uk = 4 * j + q;                 // permuted source unit
                float wx = w_ih[rr * 2 + 0] * w_l[uk] + w_ih[rr * 2 + 1] * w_l[HDIM + uk];
                float wh = w_hh[rr * HDIM + uk];
                if (g <= 1)      { af = wh + wx; a0 = wh; }
                else if (g == 2) { af = wx;      a0 = 0.f; }
                else             { af = wh;      a0 = wh; }
            } else if (j == 7 && q == 0) {                // bias column
                float bx = w_ih[rr * 2 + 0] * b_l[0] + w_ih[rr * 2 + 1] * b_l[1];
                if (g <= 1)      { af = b_ih[rr] + b_hh[rr] + bx; a0 = b_ih[rr] + b_hh[rr]; }
                else if (g == 2) { af = b_ih[rr] + bx;            a0 = b_ih[rr]; }
                else             { af = b_hh[rr];                 a0 = b_hh[rr]; }
            }
            hf[j] = (__fp16)(af * sc);
            h0[j] = (__fp16)(a0 * sc);
        }
        Afold[T] = hf;
        Azero[T] = h0;
    }
    {   // y tile (unscaled): row 0 = w_l row 0, row 1 = w_l row 1, bias at k=7
        half8 hy;
        #pragma unroll
        for (int j = 0; j < 8; ++j) {
            float v = 0.f;
            if (el < 2) {
                if (j < 5)                 v = w_l[el * HDIM + 4 * j + q];
                else if (j == 7 && q == 0) v = b_l[el];
            }
            hy[j] = (__fp16)v;
        }
        Ay = hy;
    }

    // constant word3 of the B fragment: halves (k=8q+6 -> 0, k=8q+7 -> bias)
    int w3const;
    {
        half2v c67; c67[0] = (__fp16)0.f; c67[1] = (__fp16)((q == 0) ? 1.f : 0.f);
        w3const = __builtin_bit_cast(int, c67);
    }

    // ---- per-stream state ----
    float hpA[5], hpB[5];
    half8 BfA, BfB;
    float4v CA[5], CB[5];

    auto pack_B = [&](const float* hp) -> half8 {
        int4v bi;
        bi[0] = __builtin_bit_cast(int, __builtin_amdgcn_cvt_pkrtz(hp[0], hp[1]));
        bi[1] = __builtin_bit_cast(int, __builtin_amdgcn_cvt_pkrtz(hp[2], hp[3]));
        bi[2] = __builtin_bit_cast(int, __builtin_amdgcn_cvt_pkrtz(hp[4], 0.f));
        bi[3] = w3const;
        return __builtin_bit_cast(half8, bi);
    };

    {
        const float* hbA = hidden + (size_t)eA * HDIM;
        const float* hbB = hidden + (size_t)eB * HDIM;
        #pragma unroll
        for (int T = 0; T < 5; ++T) { hpA[T] = hbA[4 * T + q]; hpB[T] = hbB[4 * T + q]; }
        BfA = pack_B(hpA);
        BfB = pack_B(hpB);
    }

    const float4v czero = {0.f, 0.f, 0.f, 0.f};

    auto issue_gates = [&](const half8* A, const half8& Bf, float4v* C) {
        #pragma unroll
        for (int T = 0; T < 5; ++T) C[T] = mfma16(A[T], Bf, czero);
    };
    auto finish_update = [&](float4v* C, float* hp, half8& Bf) {
        #pragma unroll
        for (int T = 0; T < 5; ++T) {
            // C = (-log2e*ar, -log2e*az, 2log2e*anI, 2log2e*anH)
            float r = __builtin_amdgcn_rcpf(1.f + __builtin_amdgcn_exp2f(C[T][0]));
            float z = __builtin_amdgcn_rcpf(1.f + __builtin_amdgcn_exp2f(C[T][1]));
            float npre2 = __builtin_fmaf(r, C[T][3], C[T][2]);
            float tn = __builtin_amdgcn_rcpf(1.f + __builtin_amdgcn_exp2f(npre2));
            float n = __builtin_fmaf(-2.f, tn, 1.f);
            hp[T] = __builtin_fmaf(z, hp[T] - n, n);   // (1-z)*n + z*h
        }
        Bf = pack_B(hp);
    };

    float* outA = out + (size_t)eA * 2 * step;
    float* outB = out + (size_t)eB * 2 * step;

    // step 0 (x = 0): h_0 -> h_1, both streams
    issue_gates(Azero, BfA, CA);
    issue_gates(Azero, BfB, CB);
    finish_update(CA, hpA, BfA);
    finish_update(CB, hpB, BfB);

    if ((step & 1) || step < 4) {
        // generic fallback (odd / tiny step) — simple schedule, float2 stores
        for (int t = 1; t < step; ++t) {
            issue_gates(Afold, BfA, CA);
            float4v cyA = mfma16(Ay, BfA, czero);
            issue_gates(Afold, BfB, CB);
            float4v cyB = mfma16(Ay, BfB, czero);
            if (q == 0) {
                float2 sa; sa.x = cyA[0]; sa.y = cyA[1];
                *(float2*)(outA + 2 * (step - t)) = sa;
                float2 sb; sb.x = cyB[0]; sb.y = cyB[1];
                *(float2*)(outB + 2 * (step - t)) = sb;
            }
            finish_update(CA, hpA, BfA);
            finish_update(CB, hpB, BfB);
        }
        float4v cyA = mfma16(Ay, BfA, czero);
        float4v cyB = mfma16(Ay, BfB, czero);
        if (q == 0) {
            float2 sa; sa.x = cyA[0]; sa.y = cyA[1];
            *(float2*)(outA) = sa;
            float2 sb; sb.x = cyB[0]; sb.y = cyB[1];
            *(float2*)(outB) = sb;
        }
        return;
    }

    // ---- pipelined main path (even step >= 4) ----
    // output idx k is y from h_{step-k}; pairs (k, k-1) with k odd -> 16B store.
    float4v pendA, pendB;      // {y_{k-1}, y_k} of previous pair, per stream
    float  *pendpA, *pendpB;

    {   // first pair: k0 = step-1
        issue_gates(Afold, BfA, CA);
        float4v cyA1 = mfma16(Ay, BfA, czero);       // idx step-1, stream A
        issue_gates(Afold, BfB, CB);
        float4v cyB1 = mfma16(Ay, BfB, czero);       // idx step-1, stream B
        finish_update(CA, hpA, BfA);
        finish_update(CB, hpB, BfB);
        issue_gates(Afold, BfA, CA);
        float4v cyA2 = mfma16(Ay, BfA, czero);       // idx step-2
        issue_gates(Afold, BfB, CB);
        float4v cyB2 = mfma16(Ay, BfB, czero);
        finish_update(CA, hpA, BfA);
        finish_update(CB, hpB, BfB);
        pendA[0] = cyA2[0]; pendA[1] = cyA2[1]; pendA[2] = cyA1[0]; pendA[3] = cyA1[1];
        pendB[0] = cyB2[0]; pendB[1] = cyB2[1]; pendB[2] = cyB1[0]; pendB[3] = cyB1[1];
        pendpA = outA + 2 * (step - 2);
        pendpB = outB + 2 * (step - 2);
    }

    for (int k = step - 3; k >= 3; k -= 2) {
        issue_gates(Afold, BfA, CA);
        float4v cyA1 = mfma16(Ay, BfA, czero);       // idx k
        issue_gates(Afold, BfB, CB);
        float4v cyB1 = mfma16(Ay, BfB, czero);
        if (q == 0) {                                // prev pair: data long ready
            *(float4v*)pendpA = pendA;
            *(float4v*)pendpB = pendB;
        }
        finish_update(CA, hpA, BfA);
        finish_update(CB, hpB, BfB);
        issue_gates(Afold, BfA, CA);
        float4v cyA2 = mfma16(Ay, BfA, czero);       // idx k-1
        issue_gates(Afold, BfB, CB);
        float4v cyB2 = mfma16(Ay, BfB, czero);
        finish_update(CA, hpA, BfA);
        finish_update(CB, hpB, BfB);
        pendA[0] = cyA2[0]; pendA[1] = cyA2[1]; pendA[2] = cyA1[0]; pendA[3] = cyA1[1];
        pendB[0] = cyB2[0]; pendB[1] = cyB2[1]; pendB[2] = cyB1[0]; pendB[3] = cyB1[1];
        pendpA = outA + 2 * (k - 1);
        pendpB = outB + 2 * (k - 1);
    }

    {   // last pair: k == 1
        issue_gates(Afold, BfA, CA);
        float4v cyA1 = mfma16(Ay, BfA, czero);       // idx 1
        issue_gates(Afold, BfB, CB);
        float4v cyB1 = mfma16(Ay, BfB, czero);
        if (q == 0) {
            *(float4v*)pendpA = pendA;
            *(float4v*)pendpB = pendB;
        }
        finish_update(CA, hpA, BfA);                 // BfA = h_step
        finish_update(CB, hpB, BfB);
        float4v cyA2 = mfma16(Ay, BfA, czero);       // idx 0
        float4v cyB2 = mfma16(Ay, BfB, czero);
        if (q == 0) {
            float4v sa; sa[0] = cyA2[0]; sa[1] = cyA2[1]; sa[2] = cyA1[0]; sa[3] = cyA1[1];
            *(float4v*)outA = sa;
            float4v sb; sb[0] = cyB2[0]; sb[1] = cyB2[1]; sb[2] = cyB1[0]; sb[3] = cyB1[1];
            *(float4v*)outB = sb;
        }
    }
}

extern "C" void kernel_launch(void* const* d_in, const int* in_sizes, int n_in,
                              void* d_out, int out_size, void* d_ws, size_t ws_size,
                              hipStream_t stream) {
    const float* hidden = (const float*)d_in[0];
    const float* w_ih   = (const float*)d_in[1];
    const float* w_hh   = (const float*)d_in[2];
    const float* b_ih   = (const float*)d_in[3];
    const float* b_hh   = (const float*)d_in[4];
    const float* w_l    = (const float*)d_in[5];
    const float* b_l    = (const float*)d_in[6];
    const int*   step   = (const int*)d_in[7];
    float* out = (float*)d_out;

    int B = in_sizes[0] / HDIM;     // hidden is (1, B, 20); B = 32768
    int grid = B / 128;             // 4 waves/block x 32 elements/wave (dual stream)

    gru_decoder_kernel<<<grid, BLOCK, 0, stream>>>(
        hidden, w_ih, w_hh, b_ih, b_hh, w_l, b_l, step, out, B);
}

// Round 3
// 168.978 us; speedup vs baseline: 1.1277x; 1.1277x over previous
//
#include <hip/hip_runtime.h>

#define HDIM 20
#define BLOCK 256

typedef __fp16 half8 __attribute__((ext_vector_type(8)));
typedef __fp16 half2v __attribute__((ext_vector_type(2)));
typedef float  float4v __attribute__((ext_vector_type(4)));
typedef int    int4v  __attribute__((ext_vector_type(4)));

static __device__ __forceinline__ float4v mfma16(half8 a, half8 b, float4v c) {
    return __builtin_amdgcn_mfma_f32_16x16x32_f16(a, b, c, 0, 0, 0);
}

// KEY INVARIANT (why there is NO cross-lane traffic in the 200-step loop):
//   B-row permutation: k = 8q + i  <->  hidden unit 4i + q   (i<5; i=5,6 pad; k=7(q=0) bias=1).
//   C/D layout (m89): lane (q,el) holds D rows 4q..4q+3 of column el.
//   A rows arranged so tile T, row 4q'+g = unit 4T+q', gate type g in {r,z,nI,nH}
//   -> lane (q,el) computes h_new for units {4T+q}, which are EXACTLY its own
//      B rows k=8q+T. The "allgather" is the identity: pack own h to fp16, done.
// A rows pre-scaled: r,z by -log2e ; nI,nH by +2log2e (tanh via 1-2/(1+exp2)).
//
// v4: back to v2's single-stream 2-waves/SIMD structure (v3 dual-stream
// regressed: +20% instructions, no latency coverage). New this round:
//  (a) TRANS REDUCTION 30 -> 23 ops/step: r,z share one rcp per tile via
//      inv = rcp((1+er)(1+ez)); the 5 tanh rcps pair across tiles (5 -> 3).
//      Error ~1e-7 rel, 4 orders below the fp16 state rounding. Theory: the
//      trans unit is 4-lane/cyc (16 cyc/wave64 op) and v2 was ~95%
//      trans-throughput-bound (60 ops x 16 = 960 of 1229 cyc/SIMD/step).
//  (b) wave stagger: co-resident-block parity sleeps ~640 cyc pre-loop to
//      de-phase the 2 waves/SIMD (tests the competing phase-lock theory).

__global__ __launch_bounds__(BLOCK, 2) void gru_decoder_kernel(
    const float* __restrict__ hidden,
    const float* __restrict__ w_ih,
    const float* __restrict__ w_hh,
    const float* __restrict__ b_ih,
    const float* __restrict__ b_hh,
    const float* __restrict__ w_l,
    const float* __restrict__ b_l,
    const int*  __restrict__ step_ptr,
    float* __restrict__ out,
    int B)
{
    const int tid = threadIdx.x;
    const int l   = tid & 63;
    const int wv  = tid >> 6;
    const int el  = l & 15;
    const int q   = l >> 4;
    const int e   = (blockIdx.x * 4 + wv) * 16 + el;
    const int step = *step_ptr;

    const float NL2E  = -1.4426950408889634f;   // r,z scale
    const float T2L2E =  2.8853900817779268f;   // n scale

    // ---- A fragments (once). Lane holds k=8q..8q+7; A row m=el of tile T is
    // unit 4T+(el>>2), gate type el&3 {0:r,1:z,2:nI,3:nH}. ----
    const int u_dst = el >> 2;
    const int g     = el & 3;

    half8 Afold[5], Azero[5], Ay;
    #pragma unroll
    for (int T = 0; T < 5; ++T) {
        const int u  = 4 * T + u_dst;
        const int rr = (g == 0) ? u : (g == 1) ? 20 + u : 40 + u;
        const float sc = (g <= 1) ? NL2E : T2L2E;
        half8 hf, h0;
        #pragma unroll
        for (int j = 0; j < 8; ++j) {
            float af = 0.f, a0 = 0.f;
            if (j < 5) {
                const int uk = 4 * j + q;                 // permuted source unit
                float wx = w_ih[rr * 2 + 0] * w_l[uk] + w_ih[rr * 2 + 1] * w_l[HDIM + uk];
                float wh = w_hh[rr * HDIM + uk];
                if (g <= 1)      { af = wh + wx; a0 = wh; }
                else if (g == 2) { af = wx;      a0 = 0.f; }
                else             { af = wh;      a0 = wh; }
            } else if (j == 7 && q == 0) {                // bias column
                float bx = w_ih[rr * 2 + 0] * b_l[0] + w_ih[rr * 2 + 1] * b_l[1];
                if (g <= 1)      { af = b_ih[rr] + b_hh[rr] + bx; a0 = b_ih[rr] + b_hh[rr]; }
                else if (g == 2) { af = b_ih[rr] + bx;            a0 = b_ih[rr]; }
                else             { af = b_hh[rr];                 a0 = b_hh[rr]; }
            }
            hf[j] = (__fp16)(af * sc);
            h0[j] = (__fp16)(a0 * sc);
        }
        Afold[T] = hf;
        Azero[T] = h0;
    }
    {   // y tile (unscaled): row 0 = w_l row 0, row 1 = w_l row 1, bias at k=7
        half8 hy;
        #pragma unroll
        for (int j = 0; j < 8; ++j) {
            float v = 0.f;
            if (el < 2) {
                if (j < 5)                 v = w_l[el * HDIM + 4 * j + q];
                else if (j == 7 && q == 0) v = b_l[el];
            }
            hy[j] = (__fp16)v;
        }
        Ay = hy;
    }

    // constant word3 of the B fragment: halves (k=8q+6 -> 0, k=8q+7 -> bias)
    int w3const;
    {
        half2v c67; c67[0] = (__fp16)0.f; c67[1] = (__fp16)((q == 0) ? 1.f : 0.f);
        w3const = __builtin_bit_cast(int, c67);
    }

    // ---- state init: hprev fp32; Bf = own units packed (identity allgather) ----
    float hprev[5];
    half8 Bf;
    {
        const float* hb = hidden + (size_t)e * HDIM;
        #pragma unroll
        for (int T = 0; T < 5; ++T) hprev[T] = hb[4 * T + q];
        int4v bi;
        bi[0] = __builtin_bit_cast(int, __builtin_amdgcn_cvt_pkrtz(hprev[0], hprev[1]));
        bi[1] = __builtin_bit_cast(int, __builtin_amdgcn_cvt_pkrtz(hprev[2], hprev[3]));
        bi[2] = __builtin_bit_cast(int, __builtin_amdgcn_cvt_pkrtz(hprev[4], 0.f));
        bi[3] = w3const;
        Bf = __builtin_bit_cast(half8, bi);
    }

    const float4v czero = {0.f, 0.f, 0.f, 0.f};
    float4v C[5];

    auto issue_gates = [&](const half8* A) {
        #pragma unroll
        for (int T = 0; T < 5; ++T) C[T] = mfma16(A[T], Bf, czero);
    };
    auto finish_update = [&]() {
        // C = (-log2e*ar, -log2e*az, 2log2e*anI, 2log2e*anH)
        // r = 1/(1+exp2(C0)), z = 1/(1+exp2(C1)) -- SHARED rcp per tile:
        //   inv = rcp((1+er)(1+ez)); r = (1+ez)*inv; z = (1+er)*inv.
        // tanh: tn = 1/(1+exp2(npre2)), n = 1-2*tn -- tn rcps PAIRED across tiles.
        float zz[5], en[5];
        #pragma unroll
        for (int T = 0; T < 5; ++T) {
            float er = __builtin_amdgcn_exp2f(C[T][0]);
            float ez = __builtin_amdgcn_exp2f(C[T][1]);
            float ar = 1.f + er;
            float az = 1.f + ez;
            float inv = __builtin_amdgcn_rcpf(ar * az);
            float r  = az * inv;
            zz[T]    = ar * inv;
            float npre2 = __builtin_fmaf(r, C[T][3], C[T][2]);
            en[T] = 1.f + __builtin_amdgcn_exp2f(npre2);
        }
        float tn[5];
        {
            float i01 = __builtin_amdgcn_rcpf(en[0] * en[1]);
            tn[0] = en[1] * i01;
            tn[1] = en[0] * i01;
            float i23 = __builtin_amdgcn_rcpf(en[2] * en[3]);
            tn[2] = en[3] * i23;
            tn[3] = en[2] * i23;
            tn[4] = __builtin_amdgcn_rcpf(en[4]);
        }
        #pragma unroll
        for (int T = 0; T < 5; ++T) {
            float n = __builtin_fmaf(-2.f, tn[T], 1.f);
            hprev[T] = __builtin_fmaf(zz[T], hprev[T] - n, n);   // (1-z)*n + z*h
        }
        // rebuild B fragment from own registers — no LDS, no shuffles
        int4v bi;
        bi[0] = __builtin_bit_cast(int, __builtin_amdgcn_cvt_pkrtz(hprev[0], hprev[1]));
        bi[1] = __builtin_bit_cast(int, __builtin_amdgcn_cvt_pkrtz(hprev[2], hprev[3]));
        bi[2] = __builtin_bit_cast(int, __builtin_amdgcn_cvt_pkrtz(hprev[4], 0.f));
        bi[3] = w3const;
        Bf = __builtin_bit_cast(half8, bi);
    };

    float* outp = out + (size_t)e * 2 * step;

    // de-phase the two co-resident waves per SIMD (~640 cyc, once):
    // co-resident blocks on a CU differ in (blockIdx>>3) under XCD round-robin.
    if ((blockIdx.x >> 3) & 1) __builtin_amdgcn_s_sleep(10);

    // step 0 (x = 0): h_0 -> h_1
    issue_gates(Azero);
    finish_update();

    if ((step & 1) || step < 4) {
        // generic fallback (odd / tiny step) — simple schedule, float2 stores
        for (int t = 1; t < step; ++t) {
            issue_gates(Afold);
            float4v cy = mfma16(Ay, Bf, czero);
            if (q == 0) {
                float2 st; st.x = cy[0]; st.y = cy[1];
                *(float2*)(outp + 2 * (step - t)) = st;
            }
            finish_update();
        }
        float4v cy = mfma16(Ay, Bf, czero);
        if (q == 0) {
            float2 st; st.x = cy[0]; st.y = cy[1];
            *(float2*)(outp) = st;
        }
        return;
    }

    // ---- pipelined main path (even step >= 4) ----
    // output idx k is y from h_{step-k}; pairs (k, k-1) with k odd -> 16B store.
    float4v pend;          // {y_{k-1}.x, y_{k-1}.y, y_k.x, y_k.y} of previous pair
    float*  pendp;         // its (16B-aligned) destination

    {   // first pair: k0 = step-1
        issue_gates(Afold);
        float4v cyA = mfma16(Ay, Bf, czero);      // idx step-1
        finish_update();
        issue_gates(Afold);
        float4v cyB = mfma16(Ay, Bf, czero);      // idx step-2
        finish_update();                          // cyB completes under this
        pend[0] = cyB[0]; pend[1] = cyB[1]; pend[2] = cyA[0]; pend[3] = cyA[1];
        pendp = outp + 2 * (step - 2);
    }

    for (int k = step - 3; k >= 3; k -= 2) {
        issue_gates(Afold);
        float4v cyA = mfma16(Ay, Bf, czero);      // idx k
        if (q == 0) *(float4v*)pendp = pend;      // prev pair: data long ready
        finish_update();
        issue_gates(Afold);
        float4v cyB = mfma16(Ay, Bf, czero);      // idx k-1
        finish_update();
        pend[0] = cyB[0]; pend[1] = cyB[1]; pend[2] = cyA[0]; pend[3] = cyA[1];
        pendp = outp + 2 * (k - 1);
    }

    {   // last pair: k == 1
        issue_gates(Afold);
        float4v cyA = mfma16(Ay, Bf, czero);      // idx 1
        if (q == 0) *(float4v*)pendp = pend;
        finish_update();                          // Bf = h_step
        float4v cyB = mfma16(Ay, Bf, czero);      // idx 0
        if (q == 0) {
            float4v st; st[0] = cyB[0]; st[1] = cyB[1]; st[2] = cyA[0]; st[3] = cyA[1];
            *(float4v*)outp = st;
        }
    }
}

extern "C" void kernel_launch(void* const* d_in, const int* in_sizes, int n_in,
                              void* d_out, int out_size, void* d_ws, size_t ws_size,
                              hipStream_t stream) {
    const float* hidden = (const float*)d_in[0];
    const float* w_ih   = (const float*)d_in[1];
    const float* w_hh   = (const float*)d_in[2];
    const float* b_ih   = (const float*)d_in[3];
    const float* b_hh   = (const float*)d_in[4];
    const float* w_l    = (const float*)d_in[5];
    const float* b_l    = (const float*)d_in[6];
    const int*   step   = (const int*)d_in[7];
    float* out = (float*)d_out;

    int B = in_sizes[0] / HDIM;     // hidden is (1, B, 20); B = 32768
    int grid = B / 64;              // 4 waves/block x 16 elements/wave

    gru_decoder_kernel<<<grid, BLOCK, 0, stream>>>(
        hidden, w_ih, w_hh, b_ih, b_hh, w_l, b_l, step, out, B);
}

// Round 4
// 166.138 us; speedup vs baseline: 1.1470x; 1.0171x over previous
//
#include <hip/hip_runtime.h>

#define HDIM 20
#define BLOCK 256

typedef __fp16 half8 __attribute__((ext_vector_type(8)));
typedef __fp16 half2v __attribute__((ext_vector_type(2)));
typedef float  float4v __attribute__((ext_vector_type(4)));
typedef int    int4v  __attribute__((ext_vector_type(4)));

static __device__ __forceinline__ float4v mfma16(half8 a, half8 b, float4v c) {
    return __builtin_amdgcn_mfma_f32_16x16x32_f16(a, b, c, 0, 0, 0);
}

// KEY INVARIANT (why there is NO cross-lane traffic in the 200-step loop):
//   B-row permutation: k = 8q + i  <->  hidden unit 4i + q   (i<5; i=5,6 pad; k=7(q=0) bias=1).
//   C/D layout (m89): lane (q,el) holds D rows 4q..4q+3 of column el.
//   A rows arranged so tile T, row 4q'+g = unit 4T+q', gate type g in {r,z,nI,nH}
//   -> lane (q,el) computes h_new for units {4T+q}, which are EXACTLY its own
//      B rows k=8q+T. The "allgather" is the identity: pack own h to fp16, done.
// A rows pre-scaled: r,z by -log2e ; nI,nH by +2log2e (tanh via 1-2/(1+exp2)).
//
// v5: v2 structure + STAGE-BATCHED nonlinearity. Evidence: VGPR_Count=60 ==
// exact steady-loop live set -> compiler serialized the 5 independent tile
// chains through reused temps (ILP~1, ~16cyc/instr stall). v3 proved
// interleaving halves per-instr stall (8.7 vs 16) but paid 2x ops for it.
// Here: batch each STAGE across all 5 tiles (10 exp2 | 10 add+rcp | 5 fma+
// 5 exp2 | 5 add+rcp | updates+pack) with sched_barrier(0) pinning stage
// boundaries so the scheduler cannot re-serialize into minimal registers.
// Arithmetic op-for-op identical to v2.

__global__ __launch_bounds__(BLOCK, 2) void gru_decoder_kernel(
    const float* __restrict__ hidden,
    const float* __restrict__ w_ih,
    const float* __restrict__ w_hh,
    const float* __restrict__ b_ih,
    const float* __restrict__ b_hh,
    const float* __restrict__ w_l,
    const float* __restrict__ b_l,
    const int*  __restrict__ step_ptr,
    float* __restrict__ out,
    int B)
{
    const int tid = threadIdx.x;
    const int l   = tid & 63;
    const int wv  = tid >> 6;
    const int el  = l & 15;
    const int q   = l >> 4;
    const int e   = (blockIdx.x * 4 + wv) * 16 + el;
    const int step = *step_ptr;

    const float NL2E  = -1.4426950408889634f;   // r,z scale
    const float T2L2E =  2.8853900817779268f;   // n scale

    // ---- A fragments (once). Lane holds k=8q..8q+7; A row m=el of tile T is
    // unit 4T+(el>>2), gate type el&3 {0:r,1:z,2:nI,3:nH}. ----
    const int u_dst = el >> 2;
    const int g     = el & 3;

    half8 Afold[5], Azero[5], Ay;
    #pragma unroll
    for (int T = 0; T < 5; ++T) {
        const int u  = 4 * T + u_dst;
        const int rr = (g == 0) ? u : (g == 1) ? 20 + u : 40 + u;
        const float sc = (g <= 1) ? NL2E : T2L2E;
        half8 hf, h0;
        #pragma unroll
        for (int j = 0; j < 8; ++j) {
            float af = 0.f, a0 = 0.f;
            if (j < 5) {
                const int uk = 4 * j + q;                 // permuted source unit
                float wx = w_ih[rr * 2 + 0] * w_l[uk] + w_ih[rr * 2 + 1] * w_l[HDIM + uk];
                float wh = w_hh[rr * HDIM + uk];
                if (g <= 1)      { af = wh + wx; a0 = wh; }
                else if (g == 2) { af = wx;      a0 = 0.f; }
                else             { af = wh;      a0 = wh; }
            } else if (j == 7 && q == 0) {                // bias column
                float bx = w_ih[rr * 2 + 0] * b_l[0] + w_ih[rr * 2 + 1] * b_l[1];
                if (g <= 1)      { af = b_ih[rr] + b_hh[rr] + bx; a0 = b_ih[rr] + b_hh[rr]; }
                else if (g == 2) { af = b_ih[rr] + bx;            a0 = b_ih[rr]; }
                else             { af = b_hh[rr];                 a0 = b_hh[rr]; }
            }
            hf[j] = (__fp16)(af * sc);
            h0[j] = (__fp16)(a0 * sc);
        }
        Afold[T] = hf;
        Azero[T] = h0;
    }
    {   // y tile (unscaled): row 0 = w_l row 0, row 1 = w_l row 1, bias at k=7
        half8 hy;
        #pragma unroll
        for (int j = 0; j < 8; ++j) {
            float v = 0.f;
            if (el < 2) {
                if (j < 5)                 v = w_l[el * HDIM + 4 * j + q];
                else if (j == 7 && q == 0) v = b_l[el];
            }
            hy[j] = (__fp16)v;
        }
        Ay = hy;
    }

    // constant word3 of the B fragment: halves (k=8q+6 -> 0, k=8q+7 -> bias)
    int w3const;
    {
        half2v c67; c67[0] = (__fp16)0.f; c67[1] = (__fp16)((q == 0) ? 1.f : 0.f);
        w3const = __builtin_bit_cast(int, c67);
    }

    // ---- state init: hprev fp32; Bf = own units packed (identity allgather) ----
    float hprev[5];
    half8 Bf;
    {
        const float* hb = hidden + (size_t)e * HDIM;
        #pragma unroll
        for (int T = 0; T < 5; ++T) hprev[T] = hb[4 * T + q];
        int4v bi;
        bi[0] = __builtin_bit_cast(int, __builtin_amdgcn_cvt_pkrtz(hprev[0], hprev[1]));
        bi[1] = __builtin_bit_cast(int, __builtin_amdgcn_cvt_pkrtz(hprev[2], hprev[3]));
        bi[2] = __builtin_bit_cast(int, __builtin_amdgcn_cvt_pkrtz(hprev[4], 0.f));
        bi[3] = w3const;
        Bf = __builtin_bit_cast(half8, bi);
    }

    const float4v czero = {0.f, 0.f, 0.f, 0.f};
    float4v C[5];

    auto issue_gates = [&](const half8* A) {
        #pragma unroll
        for (int T = 0; T < 5; ++T) C[T] = mfma16(A[T], Bf, czero);
    };

    // Stage-batched nonlinearity: all 5 tile chains advance in lockstep so
    // each stage's 5-10 independent ops cover each other's latency.
    // sched_barrier(0) pins stage boundaries (forces values live across).
    auto finish_update = [&]() {
        // S1: all first-stage exponentials (10 indep trans)
        float er[5], ez[5];
        #pragma unroll
        for (int T = 0; T < 5; ++T) {
            er[T] = __builtin_amdgcn_exp2f(C[T][0]);
            ez[T] = __builtin_amdgcn_exp2f(C[T][1]);
        }
        __builtin_amdgcn_sched_barrier(0);
        // S2: r,z reciprocals (10 indep add->rcp chains)
        float rr[5], zz[5];
        #pragma unroll
        for (int T = 0; T < 5; ++T) {
            rr[T] = __builtin_amdgcn_rcpf(1.f + er[T]);
            zz[T] = __builtin_amdgcn_rcpf(1.f + ez[T]);
        }
        __builtin_amdgcn_sched_barrier(0);
        // S3: n pre-activation + exponential (5 indep fma->exp2 chains)
        float en[5];
        #pragma unroll
        for (int T = 0; T < 5; ++T) {
            float npre2 = __builtin_fmaf(rr[T], C[T][3], C[T][2]);
            en[T] = __builtin_amdgcn_exp2f(npre2);
        }
        __builtin_amdgcn_sched_barrier(0);
        // S4: tanh reciprocals (5 indep add->rcp chains)
        float tn[5];
        #pragma unroll
        for (int T = 0; T < 5; ++T) {
            tn[T] = __builtin_amdgcn_rcpf(1.f + en[T]);
        }
        __builtin_amdgcn_sched_barrier(0);
        // S5: state update + pack (short indep chains, then 3 cvts)
        #pragma unroll
        for (int T = 0; T < 5; ++T) {
            float n = __builtin_fmaf(-2.f, tn[T], 1.f);
            hprev[T] = __builtin_fmaf(zz[T], hprev[T] - n, n);   // (1-z)*n + z*h
        }
        int4v bi;
        bi[0] = __builtin_bit_cast(int, __builtin_amdgcn_cvt_pkrtz(hprev[0], hprev[1]));
        bi[1] = __builtin_bit_cast(int, __builtin_amdgcn_cvt_pkrtz(hprev[2], hprev[3]));
        bi[2] = __builtin_bit_cast(int, __builtin_amdgcn_cvt_pkrtz(hprev[4], 0.f));
        bi[3] = w3const;
        Bf = __builtin_bit_cast(half8, bi);
    };

    float* outp = out + (size_t)e * 2 * step;

    // step 0 (x = 0): h_0 -> h_1
    issue_gates(Azero);
    finish_update();

    if ((step & 1) || step < 4) {
        // generic fallback (odd / tiny step) — simple schedule, float2 stores
        for (int t = 1; t < step; ++t) {
            issue_gates(Afold);
            float4v cy = mfma16(Ay, Bf, czero);
            if (q == 0) {
                float2 st; st.x = cy[0]; st.y = cy[1];
                *(float2*)(outp + 2 * (step - t)) = st;
            }
            finish_update();
        }
        float4v cy = mfma16(Ay, Bf, czero);
        if (q == 0) {
            float2 st; st.x = cy[0]; st.y = cy[1];
            *(float2*)(outp) = st;
        }
        return;
    }

    // ---- pipelined main path (even step >= 4) ----
    // output idx k is y from h_{step-k}; pairs (k, k-1) with k odd -> 16B store.
    float4v pend;          // {y_{k-1}.x, y_{k-1}.y, y_k.x, y_k.y} of previous pair
    float*  pendp;         // its (16B-aligned) destination

    {   // first pair: k0 = step-1
        issue_gates(Afold);
        float4v cyA = mfma16(Ay, Bf, czero);      // idx step-1
        finish_update();
        issue_gates(Afold);
        float4v cyB = mfma16(Ay, Bf, czero);      // idx step-2
        finish_update();                          // cyB completes under this
        pend[0] = cyB[0]; pend[1] = cyB[1]; pend[2] = cyA[0]; pend[3] = cyA[1];
        pendp = outp + 2 * (step - 2);
    }

    for (int k = step - 3; k >= 3; k -= 2) {
        issue_gates(Afold);
        float4v cyA = mfma16(Ay, Bf, czero);      // idx k
        if (q == 0) *(float4v*)pendp = pend;      // prev pair: data long ready
        finish_update();
        issue_gates(Afold);
        float4v cyB = mfma16(Ay, Bf, czero);      // idx k-1
        finish_update();
        pend[0] = cyB[0]; pend[1] = cyB[1]; pend[2] = cyA[0]; pend[3] = cyA[1];
        pendp = outp + 2 * (k - 1);
    }

    {   // last pair: k == 1
        issue_gates(Afold);
        float4v cyA = mfma16(Ay, Bf, czero);      // idx 1
        if (q == 0) *(float4v*)pendp = pend;
        finish_update();                          // Bf = h_step
        float4v cyB = mfma16(Ay, Bf, czero);      // idx 0
        if (q == 0) {
            float4v st; st[0] = cyB[0]; st[1] = cyB[1]; st[2] = cyA[0]; st[3] = cyA[1];
            *(float4v*)outp = st;
        }
    }
}

extern "C" void kernel_launch(void* const* d_in, const int* in_sizes, int n_in,
                              void* d_out, int out_size, void* d_ws, size_t ws_size,
                              hipStream_t stream) {
    const float* hidden = (const float*)d_in[0];
    const float* w_ih   = (const float*)d_in[1];
    const float* w_hh   = (const float*)d_in[2];
    const float* b_ih   = (const float*)d_in[3];
    const float* b_hh   = (const float*)d_in[4];
    const float* w_l    = (const float*)d_in[5];
    const float* b_l    = (const float*)d_in[6];
    const int*   step   = (const int*)d_in[7];
    float* out = (float*)d_out;

    int B = in_sizes[0] / HDIM;     // hidden is (1, B, 20); B = 32768
    int grid = B / 64;              // 4 waves/block x 16 elements/wave

    gru_decoder_kernel<<<grid, BLOCK, 0, stream>>>(
        hidden, w_ih, w_hh, b_ih, b_hh, w_l, b_l, step, out, B);
}